// Round 1
// baseline (193.916 us; speedup 1.0000x reference)
//
#include <hip/hip_runtime.h>
#include <stdint.h>

#define D_MODEL 1024
#define NH 16
#define DKH 64
#define BATCH 2
#define SEQ 2048
#define MROWS (BATCH * SEQ)   // 4096

typedef __bf16 bf16;
typedef __bf16 b16x8 __attribute__((ext_vector_type(8)));
typedef float f32x4 __attribute__((ext_vector_type(4)));

// async global->LDS, 16B per lane; LDS dest is wave-uniform base + lane*16 (HW)
__device__ __forceinline__ void gload_lds16(const void* g, void* l) {
  auto* gp = reinterpret_cast<const __attribute__((address_space(1))) uint32_t*>(
      reinterpret_cast<uintptr_t>(g));
  auto* lp = reinterpret_cast<__attribute__((address_space(3))) uint32_t*>(
      reinterpret_cast<uintptr_t>(l));
  __builtin_amdgcn_global_load_lds(gp, lp, 16, 0, 0);
}

// ---------------- cast q/k/v f32 -> bf16 ----------------
__global__ __launch_bounds__(256) void cast_qkv_kernel(
    const float* __restrict__ q, const float* __restrict__ k, const float* __restrict__ v,
    bf16* __restrict__ qo, bf16* __restrict__ ko, bf16* __restrict__ vo) {
  const float* in = blockIdx.z == 0 ? q : (blockIdx.z == 1 ? k : v);
  bf16* out = blockIdx.z == 0 ? qo : (blockIdx.z == 1 ? ko : vo);
  const int idx = (blockIdx.x * 256 + threadIdx.x) * 8;
  float4 a = *(const float4*)(in + idx);
  float4 b = *(const float4*)(in + idx + 4);
  b16x8 r;
  r[0] = (bf16)a.x; r[1] = (bf16)a.y; r[2] = (bf16)a.z; r[3] = (bf16)a.w;
  r[4] = (bf16)b.x; r[5] = (bf16)b.y; r[6] = (bf16)b.z; r[7] = (bf16)b.w;
  *(b16x8*)(out + idx) = r;
}

// ---------------- transpose-cast weights: W[K][N] f32 -> Wt[N][K] bf16 ----------------
__global__ void wtrans_kernel(const float* __restrict__ Wq, const float* __restrict__ Wk,
                              const float* __restrict__ Wv, const float* __restrict__ Wo,
                              bf16* __restrict__ Wqt, bf16* __restrict__ Wkt,
                              bf16* __restrict__ Wvt, bf16* __restrict__ Wot) {
  __shared__ float t[32][33];
  const float* W;
  bf16* Wt;
  switch (blockIdx.z) {
    case 0: W = Wq; Wt = Wqt; break;
    case 1: W = Wk; Wt = Wkt; break;
    case 2: W = Wv; Wt = Wvt; break;
    default: W = Wo; Wt = Wot; break;
  }
  const int bx = blockIdx.x * 32, by = blockIdx.y * 32;
  const int tx = threadIdx.x, ty = threadIdx.y;
#pragma unroll
  for (int i = 0; i < 32; i += 8)
    t[ty + i][tx] = W[(size_t)(by + ty + i) * D_MODEL + bx + tx];
  __syncthreads();
#pragma unroll
  for (int i = 0; i < 32; i += 8)
    Wt[(size_t)(bx + ty + i) * D_MODEL + by + tx] = (bf16)t[tx][ty + i];
}

// ---------------- 128x128 bf16 GEMM core (A[M][1024] @ Bt[N][1024]^T + bias) ----------------
// T2 swizzle: physical 16B-slot within each LDS row = logical_slot ^ (row & 3)
// (4 slots/row of 32-elem rows). Source pre-swizzled so global_load_lds stays linear.
__device__ __forceinline__ void gemm128(const bf16* __restrict__ A, const bf16* __restrict__ Bt,
                                        const float* __restrict__ bias,
                                        bf16* __restrict__ Cb, float* __restrict__ Cf) {
  __shared__ __align__(16) bf16 As[128 * 32];
  __shared__ __align__(16) bf16 Bs[128 * 32];
  const int tid = threadIdx.x;
  const int w = tid >> 6, lane = tid & 63;
  const int wm = w >> 1, wn = w & 1;
  const int mbase = blockIdx.y * 128, nbase = blockIdx.x * 128;
  // staging coords: each wave-issue covers 16 rows x 32 cols (lane -> row lane>>2, slot lane&3)
  const int srow = lane >> 2;
  const int scol = ((lane & 3) ^ ((lane >> 2) & 3)) * 8;  // pre-swizzled source col
  f32x4 acc[4][4] = {};
#pragma unroll 1
  for (int kt = 0; kt < D_MODEL / 32; ++kt) {
    __syncthreads();
#pragma unroll
    for (int i = 0; i < 2; ++i) {
      const int r0 = (i * 4 + w) * 16;
      gload_lds16(A + (size_t)(mbase + r0 + srow) * D_MODEL + kt * 32 + scol,
                  (char*)As + r0 * 64);
      gload_lds16(Bt + (size_t)(nbase + r0 + srow) * D_MODEL + kt * 32 + scol,
                  (char*)Bs + r0 * 64);
    }
    __syncthreads();
    b16x8 af[4], bfr[4];
    const int l15 = lane & 15, hi = lane >> 4;
#pragma unroll
    for (int m = 0; m < 4; ++m) {
      const int row = wm * 64 + m * 16 + l15;
      af[m] = *(const b16x8*)(As + row * 32 + ((hi ^ (row & 3)) * 8));
    }
#pragma unroll
    for (int n = 0; n < 4; ++n) {
      const int row = wn * 64 + n * 16 + l15;
      bfr[n] = *(const b16x8*)(Bs + row * 32 + ((hi ^ (row & 3)) * 8));
    }
#pragma unroll
    for (int m = 0; m < 4; ++m)
#pragma unroll
      for (int n = 0; n < 4; ++n)
        acc[m][n] = __builtin_amdgcn_mfma_f32_16x16x32_bf16(af[m], bfr[n], acc[m][n], 0, 0, 0);
  }
  float bv[4];
#pragma unroll
  for (int n = 0; n < 4; ++n) bv[n] = bias[nbase + wn * 64 + n * 16 + (lane & 15)];
  const int colb = nbase + wn * 64 + (lane & 15);
  const int rowb = mbase + wm * 64 + (lane >> 4) * 4;
  if (Cf) {
#pragma unroll
    for (int m = 0; m < 4; ++m)
#pragma unroll
      for (int n = 0; n < 4; ++n)
#pragma unroll
        for (int r = 0; r < 4; ++r)
          Cf[(size_t)(rowb + m * 16 + r) * D_MODEL + colb + n * 16] = acc[m][n][r] + bv[n];
  } else {
#pragma unroll
    for (int m = 0; m < 4; ++m)
#pragma unroll
      for (int n = 0; n < 4; ++n)
#pragma unroll
        for (int r = 0; r < 4; ++r)
          Cb[(size_t)(rowb + m * 16 + r) * D_MODEL + colb + n * 16] =
              (bf16)(acc[m][n][r] + bv[n]);
  }
}

__global__ __launch_bounds__(256) void gemm_qkv_kernel(
    const bf16* __restrict__ qbf, const bf16* __restrict__ kbf, const bf16* __restrict__ vbf,
    const bf16* __restrict__ Wqt, const bf16* __restrict__ Wkt, const bf16* __restrict__ Wvt,
    const float* __restrict__ bq, const float* __restrict__ bk, const float* __restrict__ bv,
    bf16* __restrict__ Qo, bf16* __restrict__ Ko, bf16* __restrict__ Vo) {
  const bf16 *A, *Bt;
  const float* bias;
  bf16* C;
  switch (blockIdx.z) {
    case 0: A = qbf; Bt = Wqt; bias = bq; C = Qo; break;
    case 1: A = kbf; Bt = Wkt; bias = bk; C = Ko; break;
    default: A = vbf; Bt = Wvt; bias = bv; C = Vo; break;
  }
  gemm128(A, Bt, bias, C, nullptr);
}

__global__ __launch_bounds__(256) void gemm_out_kernel(
    const bf16* __restrict__ Aatt, const bf16* __restrict__ Wot,
    const float* __restrict__ bo, float* __restrict__ out) {
  gemm128(Aatt, Wot, bo, nullptr, out);
}

// ---------------- flash attention: per (b,h), 128 q-rows/block ----------------
// K_lds[128][64] linear via global_load_lds, 16B-slot swizzle: phys_slot = log_slot ^ (row&7)
// Vt[64][136] transposed+padded; P per-wave [32][136] padded.
__global__ __launch_bounds__(256) void attn_kernel(
    const bf16* __restrict__ Qg, const bf16* __restrict__ Kg,
    const bf16* __restrict__ Vg, bf16* __restrict__ Og) {
  __shared__ __align__(16) bf16 Ks[128 * 64];
  __shared__ __align__(16) bf16 Vt[64 * 136];
  __shared__ __align__(16) bf16 Ps[4 * 32 * 136];
  const int tid = threadIdx.x, w = tid >> 6, lane = tid & 63;
  const int l15 = lane & 15, hi = lane >> 4;
  const int bh = blockIdx.y;
  const size_t base = (size_t)(bh >> 4) * SEQ * D_MODEL + (size_t)(bh & 15) * DKH;
  const int qbase = blockIdx.x * 128;
  // hoist Q fragments to registers
  b16x8 qf[2][2];
#pragma unroll
  for (int rf = 0; rf < 2; ++rf)
#pragma unroll
    for (int ks = 0; ks < 2; ++ks)
      qf[rf][ks] = *(const b16x8*)(Qg + base +
                                   (size_t)(qbase + w * 32 + rf * 16 + l15) * D_MODEL +
                                   ks * 32 + hi * 8);
  f32x4 oacc[2][4] = {};
  float mrow[2][4], lrow[2][4];
#pragma unroll
  for (int rf = 0; rf < 2; ++rf)
#pragma unroll
    for (int r = 0; r < 4; ++r) { mrow[rf][r] = -1e30f; lrow[rf][r] = 0.f; }
  bf16* Pw = Ps + w * (32 * 136);
  const int vrow = tid >> 1, vcg = (tid & 1) * 32;
#pragma unroll 1
  for (int kt = 0; kt < SEQ / 128; ++kt) {
    __syncthreads();
    // stage K tile: 4 issues/wave, 8 rows x 64 cols each; source pre-swizzled
#pragma unroll
    for (int i = 0; i < 4; ++i) {
      const int r0 = (i * 4 + w) * 8;
      const int gcol = ((lane & 7) ^ (lane >> 3)) * 8;
      gload_lds16(Kg + base + (size_t)(kt * 128 + r0 + (lane >> 3)) * D_MODEL + gcol,
                  (char*)Ks + r0 * 128);
    }
    // stage V transposed (reg path)
#pragma unroll
    for (int i = 0; i < 4; ++i) {
      const int c0 = vcg + i * 8;
      b16x8 vv = *(const b16x8*)(Vg + base + (size_t)(kt * 128 + vrow) * D_MODEL + c0);
#pragma unroll
      for (int j = 0; j < 8; ++j) Vt[(c0 + j) * 136 + vrow] = vv[j];
    }
    __syncthreads();
    // S = Q K^T (swizzled K reads)
    f32x4 sacc[2][8] = {};
#pragma unroll
    for (int cf = 0; cf < 8; ++cf) {
      const int row = cf * 16 + l15;
      const b16x8 k0 = *(const b16x8*)(Ks + row * 64 + ((hi ^ (row & 7)) * 8));
      const b16x8 k1 = *(const b16x8*)(Ks + row * 64 + (((4 + hi) ^ (row & 7)) * 8));
#pragma unroll
      for (int rf = 0; rf < 2; ++rf) {
        sacc[rf][cf] = __builtin_amdgcn_mfma_f32_16x16x32_bf16(qf[rf][0], k0, sacc[rf][cf], 0, 0, 0);
        sacc[rf][cf] = __builtin_amdgcn_mfma_f32_16x16x32_bf16(qf[rf][1], k1, sacc[rf][cf], 0, 0, 0);
      }
    }
    // online softmax (wave-parallel; rows live in 16-lane groups)
#pragma unroll
    for (int rf = 0; rf < 2; ++rf) {
#pragma unroll
      for (int r = 0; r < 4; ++r) {
        float mx = -1e30f;
#pragma unroll
        for (int cf = 0; cf < 8; ++cf) {
          float s = sacc[rf][cf][r] * 0.125f;
          sacc[rf][cf][r] = s;
          mx = fmaxf(mx, s);
        }
        mx = fmaxf(mx, __shfl_xor(mx, 1));
        mx = fmaxf(mx, __shfl_xor(mx, 2));
        mx = fmaxf(mx, __shfl_xor(mx, 4));
        mx = fmaxf(mx, __shfl_xor(mx, 8));
        const float mprev = mrow[rf][r];
        const float mnew = fmaxf(mprev, mx);
        const float corr = __expf(mprev - mnew);
        mrow[rf][r] = mnew;
        float rs = 0.f;
#pragma unroll
        for (int cf = 0; cf < 8; ++cf) {
          float p = __expf(sacc[rf][cf][r] - mnew);
          sacc[rf][cf][r] = p;
          rs += p;
        }
        rs += __shfl_xor(rs, 1);
        rs += __shfl_xor(rs, 2);
        rs += __shfl_xor(rs, 4);
        rs += __shfl_xor(rs, 8);
        lrow[rf][r] = lrow[rf][r] * corr + rs;
#pragma unroll
        for (int nf = 0; nf < 4; ++nf) oacc[rf][nf][r] *= corr;
      }
    }
    // P -> LDS (bf16), per-wave region, no barrier needed
#pragma unroll
    for (int rf = 0; rf < 2; ++rf)
#pragma unroll
      for (int cf = 0; cf < 8; ++cf)
#pragma unroll
        for (int r = 0; r < 4; ++r)
          Pw[(rf * 16 + hi * 4 + r) * 136 + cf * 16 + l15] = (bf16)sacc[rf][cf][r];
    // O += P @ V
#pragma unroll
    for (int ks = 0; ks < 4; ++ks) {
      b16x8 pa[2];
#pragma unroll
      for (int rf = 0; rf < 2; ++rf)
        pa[rf] = *(const b16x8*)(Pw + (rf * 16 + l15) * 136 + ks * 32 + hi * 8);
#pragma unroll
      for (int nf = 0; nf < 4; ++nf) {
        const b16x8 vb = *(const b16x8*)(Vt + (nf * 16 + l15) * 136 + ks * 32 + hi * 8);
#pragma unroll
        for (int rf = 0; rf < 2; ++rf)
          oacc[rf][nf] = __builtin_amdgcn_mfma_f32_16x16x32_bf16(pa[rf], vb, oacc[rf][nf], 0, 0, 0);
      }
    }
  }
  // finalize and store (bf16) to [B, L, D_MODEL]
#pragma unroll
  for (int rf = 0; rf < 2; ++rf) {
#pragma unroll
    for (int r = 0; r < 4; ++r) {
      const float inv = 1.0f / lrow[rf][r];
      const size_t rowoff = base + (size_t)(qbase + w * 32 + rf * 16 + hi * 4 + r) * D_MODEL;
#pragma unroll
      for (int nf = 0; nf < 4; ++nf)
        Og[rowoff + nf * 16 + l15] = (bf16)(oacc[rf][nf][r] * inv);
    }
  }
}

// ---------------- launch ----------------
extern "C" void kernel_launch(void* const* d_in, const int* in_sizes, int n_in,
                              void* d_out, int out_size, void* d_ws, size_t ws_size,
                              hipStream_t stream) {
  const float* query = (const float*)d_in[0];
  const float* key = (const float*)d_in[1];
  const float* value = (const float*)d_in[2];
  const float* Wq = (const float*)d_in[3];
  const float* bq = (const float*)d_in[4];
  const float* Wk = (const float*)d_in[5];
  const float* bk = (const float*)d_in[6];
  const float* Wv = (const float*)d_in[7];
  const float* bv = (const float*)d_in[8];
  const float* Wo = (const float*)d_in[9];
  const float* bo = (const float*)d_in[10];
  float* out = (float*)d_out;

  char* ws = (char*)d_ws;
  const size_t SZ_T = (size_t)MROWS * D_MODEL * sizeof(bf16);  // 8 MB per [4096,1024] bf16
  const size_t SZ_W = (size_t)D_MODEL * D_MODEL * sizeof(bf16);  // 2 MB
  bf16* qbf = (bf16*)(ws + 0 * SZ_T);
  bf16* kbf = (bf16*)(ws + 1 * SZ_T);
  bf16* vbf = (bf16*)(ws + 2 * SZ_T);
  bf16* Qb  = (bf16*)(ws + 3 * SZ_T);
  bf16* Kb  = (bf16*)(ws + 4 * SZ_T);
  bf16* Vb  = (bf16*)(ws + 5 * SZ_T);
  bf16* Att = (bf16*)(ws + 6 * SZ_T);
  bf16* Wqt = (bf16*)(ws + 7 * SZ_T + 0 * SZ_W);
  bf16* Wkt = (bf16*)(ws + 7 * SZ_T + 1 * SZ_W);
  bf16* Wvt = (bf16*)(ws + 7 * SZ_T + 2 * SZ_W);
  bf16* Wot = (bf16*)(ws + 7 * SZ_T + 3 * SZ_W);

  // 1) cast inputs to bf16: 4096*1024 elems / (256 thr * 8) = 2048 blocks
  cast_qkv_kernel<<<dim3(2048, 1, 3), 256, 0, stream>>>(query, key, value, qbf, kbf, vbf);
  // 2) transpose-cast weights
  wtrans_kernel<<<dim3(32, 32, 4), dim3(32, 8), 0, stream>>>(Wq, Wk, Wv, Wo, Wqt, Wkt, Wvt, Wot);
  // 3) QKV projections (bf16 out)
  gemm_qkv_kernel<<<dim3(D_MODEL / 128, MROWS / 128, 3), 256, 0, stream>>>(
      qbf, kbf, vbf, Wqt, Wkt, Wvt, bq, bk, bv, Qb, Kb, Vb);
  // 4) attention
  attn_kernel<<<dim3(SEQ / 128, BATCH * NH), 256, 0, stream>>>(Qb, Kb, Vb, Att);
  // 5) output projection (f32 out)
  gemm_out_kernel<<<dim3(D_MODEL / 128, MROWS / 128), 256, 0, stream>>>(Att, Wot, bo, out);
}

// Round 2
// 155.131 us; speedup vs baseline: 1.2500x; 1.2500x over previous
//
#include <hip/hip_runtime.h>
#include <stdint.h>

#define D_MODEL 1024
#define NH 16
#define DKH 64
#define BATCH 2
#define SEQ 2048
#define MROWS (BATCH * SEQ)   // 4096

typedef __bf16 bf16;
typedef __bf16 b16x8 __attribute__((ext_vector_type(8)));
typedef float f32x4 __attribute__((ext_vector_type(4)));
typedef float f32x16 __attribute__((ext_vector_type(16)));

// async global->LDS, 16B per lane; LDS dest is wave-uniform base + lane*16 (HW)
__device__ __forceinline__ void gload_lds16(const void* g, void* l) {
  auto* gp = reinterpret_cast<const __attribute__((address_space(1))) uint32_t*>(
      reinterpret_cast<uintptr_t>(g));
  auto* lp = reinterpret_cast<__attribute__((address_space(3))) uint32_t*>(
      reinterpret_cast<uintptr_t>(l));
  __builtin_amdgcn_global_load_lds(gp, lp, 16, 0, 0);
}

__device__ __forceinline__ uint32_t cvtpk_bf16(float lo, float hi) {
  uint32_t r;
  asm("v_cvt_pk_bf16_f32 %0, %1, %2" : "=v"(r) : "v"(lo), "v"(hi));
  return r;
}
// x' = [x.lo | y.lo], y' = [x.hi | y.hi]  (s_nop guards VALU->permlane hazard)
__device__ __forceinline__ void perm32swap(uint32_t& x, uint32_t& y) {
  asm("s_nop 1\n\tv_permlane32_swap_b32 %0, %1\n\ts_nop 1" : "+v"(x), "+v"(y));
}
#if __has_builtin(__builtin_amdgcn_exp2f)
__device__ __forceinline__ float exp2_fast(float x) { return __builtin_amdgcn_exp2f(x); }
#else
__device__ __forceinline__ float exp2_fast(float x) { return exp2f(x); }
#endif

// ---------------- cast q/k/v f32 -> bf16 ----------------
__global__ __launch_bounds__(256) void cast_qkv_kernel(
    const float* __restrict__ q, const float* __restrict__ k, const float* __restrict__ v,
    bf16* __restrict__ qo, bf16* __restrict__ ko, bf16* __restrict__ vo) {
  const float* in = blockIdx.z == 0 ? q : (blockIdx.z == 1 ? k : v);
  bf16* out = blockIdx.z == 0 ? qo : (blockIdx.z == 1 ? ko : vo);
  const int idx = (blockIdx.x * 256 + threadIdx.x) * 8;
  float4 a = *(const float4*)(in + idx);
  float4 b = *(const float4*)(in + idx + 4);
  b16x8 r;
  r[0] = (bf16)a.x; r[1] = (bf16)a.y; r[2] = (bf16)a.z; r[3] = (bf16)a.w;
  r[4] = (bf16)b.x; r[5] = (bf16)b.y; r[6] = (bf16)b.z; r[7] = (bf16)b.w;
  *(b16x8*)(out + idx) = r;
}

// ---------------- transpose-cast weights: W[K][N] f32 -> Wt[N][K] bf16 ----------------
__global__ void wtrans_kernel(const float* __restrict__ Wq, const float* __restrict__ Wk,
                              const float* __restrict__ Wv, const float* __restrict__ Wo,
                              bf16* __restrict__ Wqt, bf16* __restrict__ Wkt,
                              bf16* __restrict__ Wvt, bf16* __restrict__ Wot) {
  __shared__ float t[32][33];
  const float* W;
  bf16* Wt;
  switch (blockIdx.z) {
    case 0: W = Wq; Wt = Wqt; break;
    case 1: W = Wk; Wt = Wkt; break;
    case 2: W = Wv; Wt = Wvt; break;
    default: W = Wo; Wt = Wot; break;
  }
  const int bx = blockIdx.x * 32, by = blockIdx.y * 32;
  const int tx = threadIdx.x, ty = threadIdx.y;
#pragma unroll
  for (int i = 0; i < 32; i += 8)
    t[ty + i][tx] = W[(size_t)(by + ty + i) * D_MODEL + bx + tx];
  __syncthreads();
#pragma unroll
  for (int i = 0; i < 32; i += 8)
    Wt[(size_t)(bx + ty + i) * D_MODEL + by + tx] = (bf16)t[tx][ty + i];
}

// ---------------- 128x128 bf16 GEMM core (A[M][1024] @ Bt[N][1024]^T + bias) ----------------
__device__ __forceinline__ void gemm128(const bf16* __restrict__ A, const bf16* __restrict__ Bt,
                                        const float* __restrict__ bias,
                                        bf16* __restrict__ Cb, float* __restrict__ Cf) {
  __shared__ __align__(16) bf16 As[128 * 32];
  __shared__ __align__(16) bf16 Bs[128 * 32];
  const int tid = threadIdx.x;
  const int w = tid >> 6, lane = tid & 63;
  const int wm = w >> 1, wn = w & 1;
  const int mbase = blockIdx.y * 128, nbase = blockIdx.x * 128;
  const int srow = lane >> 2;
  const int scol = ((lane & 3) ^ ((lane >> 2) & 3)) * 8;  // pre-swizzled source col
  f32x4 acc[4][4] = {};
#pragma unroll 1
  for (int kt = 0; kt < D_MODEL / 32; ++kt) {
    __syncthreads();
#pragma unroll
    for (int i = 0; i < 2; ++i) {
      const int r0 = (i * 4 + w) * 16;
      gload_lds16(A + (size_t)(mbase + r0 + srow) * D_MODEL + kt * 32 + scol,
                  (char*)As + r0 * 64);
      gload_lds16(Bt + (size_t)(nbase + r0 + srow) * D_MODEL + kt * 32 + scol,
                  (char*)Bs + r0 * 64);
    }
    __syncthreads();
    b16x8 af[4], bfr[4];
    const int l15 = lane & 15, hi = lane >> 4;
#pragma unroll
    for (int m = 0; m < 4; ++m) {
      const int row = wm * 64 + m * 16 + l15;
      af[m] = *(const b16x8*)(As + row * 32 + ((hi ^ (row & 3)) * 8));
    }
#pragma unroll
    for (int n = 0; n < 4; ++n) {
      const int row = wn * 64 + n * 16 + l15;
      bfr[n] = *(const b16x8*)(Bs + row * 32 + ((hi ^ (row & 3)) * 8));
    }
#pragma unroll
    for (int m = 0; m < 4; ++m)
#pragma unroll
      for (int n = 0; n < 4; ++n)
        acc[m][n] = __builtin_amdgcn_mfma_f32_16x16x32_bf16(af[m], bfr[n], acc[m][n], 0, 0, 0);
  }
  float bv[4];
#pragma unroll
  for (int n = 0; n < 4; ++n) bv[n] = bias[nbase + wn * 64 + n * 16 + (lane & 15)];
  const int colb = nbase + wn * 64 + (lane & 15);
  const int rowb = mbase + wm * 64 + (lane >> 4) * 4;
  if (Cf) {
#pragma unroll
    for (int m = 0; m < 4; ++m)
#pragma unroll
      for (int n = 0; n < 4; ++n)
#pragma unroll
        for (int r = 0; r < 4; ++r)
          Cf[(size_t)(rowb + m * 16 + r) * D_MODEL + colb + n * 16] = acc[m][n][r] + bv[n];
  } else {
#pragma unroll
    for (int m = 0; m < 4; ++m)
#pragma unroll
      for (int n = 0; n < 4; ++n)
#pragma unroll
        for (int r = 0; r < 4; ++r)
          Cb[(size_t)(rowb + m * 16 + r) * D_MODEL + colb + n * 16] =
              (bf16)(acc[m][n][r] + bv[n]);
  }
}

__global__ __launch_bounds__(256) void gemm_qkv_kernel(
    const bf16* __restrict__ qbf, const bf16* __restrict__ kbf, const bf16* __restrict__ vbf,
    const bf16* __restrict__ Wqt, const bf16* __restrict__ Wkt, const bf16* __restrict__ Wvt,
    const float* __restrict__ bq, const float* __restrict__ bk, const float* __restrict__ bv,
    bf16* __restrict__ Qo, bf16* __restrict__ Ko, bf16* __restrict__ Vo) {
  const bf16 *A, *Bt;
  const float* bias;
  bf16* C;
  switch (blockIdx.z) {
    case 0: A = qbf; Bt = Wqt; bias = bq; C = Qo; break;
    case 1: A = kbf; Bt = Wkt; bias = bk; C = Ko; break;
    default: A = vbf; Bt = Wvt; bias = bv; C = Vo; break;
  }
  gemm128(A, Bt, bias, C, nullptr);
}

__global__ __launch_bounds__(256) void gemm_out_kernel(
    const bf16* __restrict__ Aatt, const bf16* __restrict__ Wot,
    const float* __restrict__ bo, float* __restrict__ out) {
  gemm128(Aatt, Wot, bo, nullptr, out);
}

// ---------------- flash attention, swapped-QK^T, 32x32x16 MFMA ----------------
// Per block: 128 q-rows (4 waves x 32 q), KVBLK=128 per tile.
// S^T = mfma(K_frag, Q_frag): lane holds P-col for q = lane&31 -> in-lane softmax.
// P^T -> PV B-frags via cvt_pk_bf16 + permlane32_swap (no LDS round trip).
// O^T = mfma(V^T_frag, P^T_frag); epilogue transposes via reused LDS.
__global__ __launch_bounds__(256) void attn_kernel(
    const bf16* __restrict__ Qg, const bf16* __restrict__ Kg,
    const bf16* __restrict__ Vg, bf16* __restrict__ Og) {
  __shared__ __align__(16) char smem[16384 + 17408];  // Ks [128][64] + Vt [64][136]
  bf16* Ks = (bf16*)smem;
  bf16* Vt = (bf16*)(smem + 16384);
  uint32_t* Vt32 = (uint32_t*)Vt;
  const int tid = threadIdx.x, w = tid >> 6, lane = tid & 63;
  const int l31 = lane & 31, b5 = lane >> 5;
  // XCD-aware swizzle: cluster the 16 q-blocks of one (b,h) on one XCD (512 % 8 == 0)
  int lin = blockIdx.y * gridDim.x + blockIdx.x;
  lin = (lin & 7) * 64 + (lin >> 3);
  const int bx = lin & 15, bh = lin >> 4;
  const size_t base = (size_t)(bh >> 4) * SEQ * D_MODEL + (size_t)(bh & 15) * DKH;
  const int qbase = bx * 128;

  // Q fragments (B-operand): n = q = l31, contraction d = ds*16 + 8*b5 + j
  b16x8 qf[4];
#pragma unroll
  for (int ds = 0; ds < 4; ++ds)
    qf[ds] = *(const b16x8*)(Qg + base + (size_t)(qbase + w * 32 + l31) * D_MODEL +
                             ds * 16 + b5 * 8);

  f32x16 oacc[2] = {};
  float m_run = -1e30f, l_run = 0.f;
  const float c1 = 0.18033688011112042f;  // 0.125 * log2(e)
  const int ksl = (lane & 7) ^ (lane >> 3);  // pre-swizzled K source slot

#pragma unroll 1
  for (int kt = 0; kt < SEQ / 128; ++kt) {
    // V loads early (regs only, overlap with prior compute tail)
    const bf16* vsrc = Vg + base + (size_t)(kt * 128 + 2 * lane) * D_MODEL + w * 8;
    b16x8 va0 = *(const b16x8*)(vsrc);
    b16x8 va1 = *(const b16x8*)(vsrc + D_MODEL);
    b16x8 vb0 = *(const b16x8*)(vsrc + 32);
    b16x8 vb1 = *(const b16x8*)(vsrc + D_MODEL + 32);
    __syncthreads();
    // K -> LDS, swizzled source, linear dest (phys slot = logical ^ (row&7))
#pragma unroll
    for (int i = 0; i < 4; ++i) {
      const int r0 = (i * 4 + w) * 8;
      gload_lds16(Kg + base + (size_t)(kt * 128 + r0 + (lane >> 3)) * D_MODEL + ksl * 8,
                  (char*)Ks + r0 * 128);
    }
    // V transpose: packed b32 writes, 2-way bank aliasing (free)
    union U8 { b16x8 h; uint16_t u[8]; };
    U8 ua0{va0}, ua1{va1}, ub0{vb0}, ub1{vb1};
#pragma unroll
    for (int j = 0; j < 8; ++j) {
      Vt32[(w * 8 + j) * 68 + lane] = (uint32_t)ua0.u[j] | ((uint32_t)ua1.u[j] << 16);
      Vt32[(w * 8 + 32 + j) * 68 + lane] = (uint32_t)ub0.u[j] | ((uint32_t)ub1.u[j] << 16);
    }
    __syncthreads();

    // QK^T swapped: sacc[ch] = S^T[k = ch*32 + (r&3)+8*(r>>2)+4*b5][q = l31]
    f32x16 sacc[4] = {};
    __builtin_amdgcn_s_setprio(1);
#pragma unroll
    for (int ds = 0; ds < 4; ++ds) {
#pragma unroll
      for (int ch = 0; ch < 4; ++ch) {
        const int krow = ch * 32 + l31;
        const int sl = (ds * 2 + b5) ^ (krow & 7);
        const b16x8 kf = *(const b16x8*)(Ks + krow * 64 + sl * 8);
        sacc[ch] = __builtin_amdgcn_mfma_f32_32x32x16_bf16(kf, qf[ds], sacc[ch], 0, 0, 0);
      }
    }
    __builtin_amdgcn_s_setprio(0);

    // online softmax: all 64 k-values of this lane's q are in-lane (+1 cross-half shfl)
    float mx = -1e30f;
#pragma unroll
    for (int ch = 0; ch < 4; ++ch)
#pragma unroll
      for (int r = 0; r < 16; ++r) {
        float s = sacc[ch][r] * c1;
        sacc[ch][r] = s;
        mx = fmaxf(mx, s);
      }
    mx = fmaxf(mx, __shfl_xor(mx, 32));
    const float mnew = fmaxf(m_run, mx);
    const float corr = exp2_fast(m_run - mnew);
    m_run = mnew;
    float rs = 0.f;
#pragma unroll
    for (int ch = 0; ch < 4; ++ch)
#pragma unroll
      for (int r = 0; r < 16; ++r) {
        float p = exp2_fast(sacc[ch][r] - mnew);
        sacc[ch][r] = p;
        rs += p;
      }
    rs += __shfl_xor(rs, 32);
    l_run = l_run * corr + rs;
#pragma unroll
    for (int n = 0; n < 2; ++n)
#pragma unroll
      for (int r = 0; r < 16; ++r) oacc[n][r] *= corr;

    // pack P^T -> PV B-fragments: kchunk = 2*ch + cc, word jw: {x0,x1,y0,y1}
    b16x8 pb[8];
#pragma unroll
    for (int ch = 0; ch < 4; ++ch) {
#pragma unroll
      for (int cc = 0; cc < 2; ++cc) {
        uint32_t x0 = cvtpk_bf16(sacc[ch][cc * 8 + 0], sacc[ch][cc * 8 + 1]);
        uint32_t y0 = cvtpk_bf16(sacc[ch][cc * 8 + 4], sacc[ch][cc * 8 + 5]);
        uint32_t x1 = cvtpk_bf16(sacc[ch][cc * 8 + 2], sacc[ch][cc * 8 + 3]);
        uint32_t y1 = cvtpk_bf16(sacc[ch][cc * 8 + 6], sacc[ch][cc * 8 + 7]);
        perm32swap(x0, y0);
        perm32swap(x1, y1);
        union { uint32_t u[4]; b16x8 v; } pk;
        pk.u[0] = x0; pk.u[1] = x1; pk.u[2] = y0; pk.u[3] = y1;
        pb[ch * 2 + cc] = pk.v;
      }
    }

    // PV: O^T[d][q] += V^T frags (A) x P^T frags (B)
    __builtin_amdgcn_s_setprio(1);
#pragma unroll
    for (int kc = 0; kc < 8; ++kc) {
#pragma unroll
      for (int n = 0; n < 2; ++n) {
        const int d = n * 32 + l31;
        const b16x8 vf = *(const b16x8*)(Vt + d * 136 + kc * 16 + b5 * 8);
        oacc[n] = __builtin_amdgcn_mfma_f32_32x32x16_bf16(vf, pb[kc], oacc[n], 0, 0, 0);
      }
    }
    __builtin_amdgcn_s_setprio(0);
  }

  // epilogue: normalize, transpose O^T -> O via reused LDS (per-wave [32 q][72 elems])
  const float inv = 1.f / l_run;
  __syncthreads();
  uint32_t* Otw = (uint32_t*)smem + w * (32 * 36);
#pragma unroll
  for (int n = 0; n < 2; ++n)
#pragma unroll
    for (int r2 = 0; r2 < 4; ++r2)
#pragma unroll
      for (int rp = 0; rp < 2; ++rp) {
        uint32_t pk = cvtpk_bf16(oacc[n][4 * r2 + 2 * rp] * inv,
                                 oacc[n][4 * r2 + 2 * rp + 1] * inv);
        Otw[l31 * 36 + n * 16 + r2 * 4 + b5 * 2 + rp] = pk;
      }
  __syncthreads();
  const int q = lane >> 1, half = lane & 1;
  const uint32_t* src = (uint32_t*)smem + w * (32 * 36) + q * 36 + half * 16;
  bf16* dst = Og + base + (size_t)(qbase + w * 32 + q) * D_MODEL + half * 32;
#pragma unroll
  for (int t = 0; t < 4; ++t)
    *(b16x8*)(dst + t * 8) = *(const b16x8*)(src + t * 4);
}

// ---------------- launch ----------------
extern "C" void kernel_launch(void* const* d_in, const int* in_sizes, int n_in,
                              void* d_out, int out_size, void* d_ws, size_t ws_size,
                              hipStream_t stream) {
  const float* query = (const float*)d_in[0];
  const float* key = (const float*)d_in[1];
  const float* value = (const float*)d_in[2];
  const float* Wq = (const float*)d_in[3];
  const float* bq = (const float*)d_in[4];
  const float* Wk = (const float*)d_in[5];
  const float* bk = (const float*)d_in[6];
  const float* Wv = (const float*)d_in[7];
  const float* bv = (const float*)d_in[8];
  const float* Wo = (const float*)d_in[9];
  const float* bo = (const float*)d_in[10];
  float* out = (float*)d_out;

  char* ws = (char*)d_ws;
  const size_t SZ_T = (size_t)MROWS * D_MODEL * sizeof(bf16);    // 8 MB
  const size_t SZ_W = (size_t)D_MODEL * D_MODEL * sizeof(bf16);  // 2 MB
  bf16* qbf = (bf16*)(ws + 0 * SZ_T);
  bf16* kbf = (bf16*)(ws + 1 * SZ_T);
  bf16* vbf = (bf16*)(ws + 2 * SZ_T);
  bf16* Qb  = (bf16*)(ws + 3 * SZ_T);
  bf16* Kb  = (bf16*)(ws + 4 * SZ_T);
  bf16* Vb  = (bf16*)(ws + 5 * SZ_T);
  bf16* Att = (bf16*)(ws + 6 * SZ_T);
  bf16* Wqt = (bf16*)(ws + 7 * SZ_T + 0 * SZ_W);
  bf16* Wkt = (bf16*)(ws + 7 * SZ_T + 1 * SZ_W);
  bf16* Wvt = (bf16*)(ws + 7 * SZ_T + 2 * SZ_W);
  bf16* Wot = (bf16*)(ws + 7 * SZ_T + 3 * SZ_W);

  cast_qkv_kernel<<<dim3(2048, 1, 3), 256, 0, stream>>>(query, key, value, qbf, kbf, vbf);
  wtrans_kernel<<<dim3(32, 32, 4), dim3(32, 8), 0, stream>>>(Wq, Wk, Wv, Wo, Wqt, Wkt, Wvt, Wot);
  gemm_qkv_kernel<<<dim3(D_MODEL / 128, MROWS / 128, 3), 256, 0, stream>>>(
      qbf, kbf, vbf, Wqt, Wkt, Wvt, bq, bk, bv, Qb, Kb, Vb);
  attn_kernel<<<dim3(SEQ / 128, BATCH * NH), 256, 0, stream>>>(Qb, Kb, Vb, Att);
  gemm_out_kernel<<<dim3(D_MODEL / 128, MROWS / 128), 256, 0, stream>>>(Att, Wot, bo, out);
}